// Round 7
// baseline (525.701 us; speedup 1.0000x reference)
//
#include <hip/hip_runtime.h>

#define NN 50000
#define HH 8
#define ALPHA 0.2f
#define NPAD 50048   // NN rounded up to 128

typedef short short8 __attribute__((ext_vector_type(8)));
typedef float f32x4 __attribute__((ext_vector_type(4)));

__device__ __forceinline__ float elu_f(float x) {
  return x > 0.f ? x : __expf(x) - 1.f;
}

__device__ __forceinline__ unsigned short f2bf(float f) {
  unsigned int u = __float_as_uint(f);
  unsigned int r = (u + 0x7fffu + ((u >> 16) & 1u)) >> 16;
  return (unsigned short)r;
}

// ---------------- weight prep: W [H][256][64] -> Wt [H][64][256]; Wo [512][64] -> Wot [64][512]
__global__ void cvt_w_kernel(const float* __restrict__ W, unsigned short* __restrict__ Wt,
                             const float* __restrict__ Wo, unsigned short* __restrict__ Wot) {
  int tid = blockIdx.x * 256 + threadIdx.x;
  if (tid < HH * 256 * 64) {
    int h = tid / (256 * 64);
    int rem = tid - h * 256 * 64;
    int k = rem >> 6, c = rem & 63;
    Wt[((size_t)h * 64 + c) * 256 + k] = f2bf(W[tid]);
    return;
  }
  int t2 = tid - HH * 256 * 64;
  if (t2 < 512 * 64) {
    int k = t2 >> 6, c = t2 & 63;
    Wot[(size_t)c * 512 + k] = f2bf(Wo[t2]);
  }
}

// ---------------- CSR build (dst-quasi-sorted) ----------------
// cnt2[0..N) = src histogram, cnt2[N..2N) = dst histogram
__global__ void hist_both_kernel(const int* __restrict__ src, const int* __restrict__ dst,
                                 int* __restrict__ cnt2, int N, int E) {
  int e = blockIdx.x * blockDim.x + threadIdx.x;
  if (e < E) {
    atomicAdd(&cnt2[src[e]], 1);
    atomicAdd(&cnt2[N + dst[e]], 1);
  }
}

// batched scan over two adjacent N-length arrays (grid.y = 0: src, 1: dst)
__global__ __launch_bounds__(1024) void scan_blocks2_kernel(const int* __restrict__ cnt2,
    int* __restrict__ tmp2, int* __restrict__ bsum2, int n) {
  __shared__ int sh[1024];
  int y = blockIdx.y;
  int i = blockIdx.x * 1024 + threadIdx.x;
  int v = (i < n) ? cnt2[(size_t)y * n + i] : 0;
  sh[threadIdx.x] = v;
  __syncthreads();
  for (int off = 1; off < 1024; off <<= 1) {
    int t = (threadIdx.x >= off) ? sh[threadIdx.x - off] : 0;
    __syncthreads();
    sh[threadIdx.x] += t;
    __syncthreads();
  }
  if (i < n) tmp2[(size_t)y * n + i] = sh[threadIdx.x] - v;
  if (threadIdx.x == 1023) bsum2[y * 64 + blockIdx.x] = sh[1023];
}

__global__ __launch_bounds__(128) void scan_top2_kernel(const int* __restrict__ bsum2,
    int* __restrict__ boffs2, int nb) {
  int y = threadIdx.x >> 6, L = threadIdx.x & 63;
  int v = (L < nb) ? bsum2[y * 64 + L] : 0;
  int incl = v;
#pragma unroll
  for (int off = 1; off < 64; off <<= 1) {
    int t = __shfl_up(incl, off, 64);
    if (L >= off) incl += t;
  }
  if (L < nb) boffs2[y * 64 + L] = incl - v;
}

__global__ __launch_bounds__(1024) void scan_apply2_kernel(const int* __restrict__ tmp2,
    const int* __restrict__ boffs2, int* __restrict__ row_ptr, int* __restrict__ nxt,
    int* __restrict__ nxtd, int n, int E) {
  int y = blockIdx.y;
  int i = blockIdx.x * 1024 + threadIdx.x;
  if (i < n) {
    int s = tmp2[(size_t)y * n + i] + boffs2[y * 64 + blockIdx.x];
    if (y == 0) { row_ptr[i] = s; nxt[i] = s; }
    else nxtd[i] = s;
  }
  if (i == 0 && y == 0) row_ptr[n] = E;
}

// scatter edge ids in dst order -> eid is a dst-sorted permutation of edges
__global__ void scatter_d_kernel(const int* __restrict__ dst, int* __restrict__ nxtd,
                                 int* __restrict__ eid, int E) {
  int e = blockIdx.x * blockDim.x + threadIdx.x;
  if (e < E) {
    int p = atomicAdd(&nxtd[dst[e]], 1);
    eid[p] = e;
  }
}

// walk eid in order; each row's col list ends up quasi-sorted by dst
__global__ void scatter_s_kernel(const int* __restrict__ src, const int* __restrict__ dst,
                                 const int* __restrict__ eid, int* __restrict__ nxt,
                                 int* __restrict__ col, int E) {
  int k = blockIdx.x * blockDim.x + threadIdx.x;
  if (k < E) {
    int e = eid[k];
    int p = atomicAdd(&nxt[src[e]], 1);
    col[p] = dst[e];
  }
}

// ---------------- layer-1 MFMA GEMM: x fp32 read directly, loop over 8 heads ----------------
__global__ __launch_bounds__(256) void mfma_gemm1_kernel(
    const float* __restrict__ X, const unsigned short* __restrict__ Bt,
    const float* __restrict__ Aatt, unsigned short* __restrict__ Cout,
    float* __restrict__ ss, float* __restrict__ sd, int N) {
  __shared__ unsigned short Bs[64][264];
  int w = threadIdx.x >> 6, L = threadIdx.x & 63;
  int quad = L >> 4, l16 = L & 15;
  int m0 = blockIdx.x * 64;
  int myrow = m0 + w * 16 + l16;
  int rowc = min(myrow, N - 1);          // clamp pad rows (results discarded)

  // A fragments for whole K=256, converted fp32->bf16 inline: 8 x short8
  const float* Ar = X + (size_t)rowc * 256 + quad * 8;
  short8 areg[8];
#pragma unroll
  for (int ks = 0; ks < 8; ++ks) {
    float4 a0 = *(const float4*)(Ar + ks * 32);
    float4 a1 = *(const float4*)(Ar + ks * 32 + 4);
    areg[ks][0] = (short)f2bf(a0.x); areg[ks][1] = (short)f2bf(a0.y);
    areg[ks][2] = (short)f2bf(a0.z); areg[ks][3] = (short)f2bf(a0.w);
    areg[ks][4] = (short)f2bf(a1.x); areg[ks][5] = (short)f2bf(a1.y);
    areg[ks][6] = (short)f2bf(a1.z); areg[ks][7] = (short)f2bf(a1.w);
  }

  for (int y = 0; y < HH; ++y) {
    __syncthreads();
    {
      const unsigned short* Bsrc = Bt + (size_t)y * 64 * 256;
      for (int c = threadIdx.x; c < 2048; c += 256) {
        int n = c >> 5;
        int kq = (c & 31) << 3;
        *(uint4*)&Bs[n][kq] = *(const uint4*)(Bsrc + (size_t)n * 256 + kq);
      }
    }
    __syncthreads();

    f32x4 acc[4];
#pragma unroll
    for (int nt = 0; nt < 4; ++nt) acc[nt] = (f32x4)(0.f);
#pragma unroll
    for (int ks = 0; ks < 8; ++ks) {
#pragma unroll
      for (int nt = 0; nt < 4; ++nt) {
        short8 b = *(const short8*)&Bs[l16 + 16 * nt][ks * 32 + quad * 8];
        acc[nt] = __builtin_amdgcn_mfma_f32_16x16x32_bf16(areg[ks], b, acc[nt], 0, 0, 0);
      }
    }

    float as[4], ad[4];
#pragma unroll
    for (int nt = 0; nt < 4; ++nt) {
      as[nt] = Aatt[y * 128 + l16 + 16 * nt];
      ad[nt] = Aatt[y * 128 + 64 + l16 + 16 * nt];
    }
#pragma unroll
    for (int reg = 0; reg < 4; ++reg) {
      float p = 0.f, q = 0.f;
#pragma unroll
      for (int nt = 0; nt < 4; ++nt) {
        p += acc[nt][reg] * as[nt];
        q += acc[nt][reg] * ad[nt];
      }
#pragma unroll
      for (int off = 1; off < 16; off <<= 1) {
        p += __shfl_xor(p, off, 64);
        q += __shfl_xor(q, off, 64);
      }
      int row = m0 + w * 16 + quad * 4 + reg;
      if (l16 == 0 && row < N) {
        ss[(size_t)row * 8 + y] = p;
        sd[(size_t)row * 8 + y] = q;
      }
    }
#pragma unroll
    for (int reg = 0; reg < 4; ++reg) {
      int row = m0 + w * 16 + quad * 4 + reg;
      if (row < N) {
#pragma unroll
        for (int nt = 0; nt < 4; ++nt)
          Cout[(size_t)row * 512 + y * 64 + l16 + 16 * nt] = f2bf(acc[nt][reg]);
      }
    }
  }
}

// ---------------- layer-2 MFMA GEMM ----------------
__global__ __launch_bounds__(256) void mfma_gemm2_kernel(
    const unsigned short* __restrict__ A, const unsigned short* __restrict__ Bt,
    const float* __restrict__ Aatt, unsigned short* __restrict__ Cout,
    float* __restrict__ ss, float* __restrict__ sd, int N) {
  __shared__ unsigned short Bs[64][520];
  {
    for (int c = threadIdx.x; c < 4096; c += 256) {
      int n = c >> 6;
      int kq = (c & 63) << 3;
      *(uint4*)&Bs[n][kq] = *(const uint4*)(Bt + (size_t)n * 512 + kq);
    }
  }
  __syncthreads();

  int w = threadIdx.x >> 6, L = threadIdx.x & 63;
  int quad = L >> 4, l16 = L & 15;
  int m0 = blockIdx.x * 64;
  int myrow = m0 + w * 16 + l16;
  const unsigned short* Ar = A + (size_t)myrow * 512 + quad * 8;

  f32x4 acc[4];
#pragma unroll
  for (int nt = 0; nt < 4; ++nt) acc[nt] = (f32x4)(0.f);

  short8 a_cur = *(const short8*)(Ar);
  for (int k0 = 0; k0 < 512; k0 += 32) {
    short8 a_nxt;
    if (k0 + 32 < 512) a_nxt = *(const short8*)(Ar + k0 + 32);
#pragma unroll
    for (int nt = 0; nt < 4; ++nt) {
      short8 b = *(const short8*)&Bs[l16 + 16 * nt][k0 + quad * 8];
      acc[nt] = __builtin_amdgcn_mfma_f32_16x16x32_bf16(a_cur, b, acc[nt], 0, 0, 0);
    }
    a_cur = a_nxt;
  }

  float as[4], ad[4];
#pragma unroll
  for (int nt = 0; nt < 4; ++nt) {
    as[nt] = Aatt[l16 + 16 * nt];
    ad[nt] = Aatt[64 + l16 + 16 * nt];
  }
#pragma unroll
  for (int reg = 0; reg < 4; ++reg) {
    float p = 0.f, q = 0.f;
#pragma unroll
    for (int nt = 0; nt < 4; ++nt) {
      p += acc[nt][reg] * as[nt];
      q += acc[nt][reg] * ad[nt];
    }
#pragma unroll
    for (int off = 1; off < 16; off <<= 1) {
      p += __shfl_xor(p, off, 64);
      q += __shfl_xor(q, off, 64);
    }
    int row = m0 + w * 16 + quad * 4 + reg;
    if (l16 == 0 && row < N) { ss[row] = p; sd[row] = q; }
  }
#pragma unroll
  for (int reg = 0; reg < 4; ++reg) {
    int row = m0 + w * 16 + quad * 4 + reg;
    if (row < N) {
#pragma unroll
      for (int nt = 0; nt < 4; ++nt)
        Cout[(size_t)row * 64 + l16 + 16 * nt] = f2bf(acc[nt][reg]);
    }
  }
}

// ---------------- layer-1 aggregation (unchanged structure, dst-sorted cols) ----------------
__global__ __launch_bounds__(256) void agg1_kernel(const unsigned short* __restrict__ table,
    const float* __restrict__ ss, const float* __restrict__ sd,
    const int* __restrict__ row_ptr, const int* __restrict__ col,
    unsigned short* __restrict__ xc, int N) {
  int wid = threadIdx.x >> 6, L = threadIdx.x & 63;
  int n = blockIdx.x * 4 + wid;
  if (n >= N) return;
  int h = L >> 3;
  int b = L & 7;
  int srcsel = h << 3;
  float ssn = ss[n * 8 + h];
  int k0 = row_ptr[n], deg = row_ptr[n + 1] - k0;
  float acc[8];
#pragma unroll
  for (int t = 0; t < 8; ++t) acc[t] = 0.f;
  float rs = 0.f;

  for (int c0 = 0; c0 < deg; c0 += 64) {
    int j = c0 + L;
    int d_l = (j < deg) ? col[k0 + j] : 0;
    int m = min(64, deg - c0);
    for (int g = 0; g < m; g += 8) {
      int eoff = g + b;
      int de = __shfl(d_l, eoff, 64);
      float s = ssn + sd[(size_t)de * 8 + h];
      float e = __expf(-fmaxf(s, ALPHA * s));
      if (eoff >= m) e = 0.f;
      rs += e;
      int gm = min(8, m - g);
      uint4 rv[8];
#pragma unroll
      for (int t = 0; t < 8; ++t) {
        if (t < gm) {
          int dg = __builtin_amdgcn_readlane(d_l, g + t);
          rv[t] = *((const uint4*)(table + (size_t)dg * 512) + L);
        }
      }
#pragma unroll
      for (int t = 0; t < 8; ++t) {
        if (t < gm) {
          float ew = __shfl(e, srcsel + t, 64);
          const unsigned int* up = (const unsigned int*)&rv[t];
#pragma unroll
          for (int v = 0; v < 4; ++v) {
            acc[2 * v]     += ew * __uint_as_float(up[v] << 16);
            acc[2 * v + 1] += ew * __uint_as_float(up[v] & 0xffff0000u);
          }
        }
      }
    }
  }
  rs += __shfl_xor(rs, 1, 64);
  rs += __shfl_xor(rs, 2, 64);
  rs += __shfl_xor(rs, 4, 64);
  float inv = 1.f / rs;
  short8 pk;
#pragma unroll
  for (int t = 0; t < 8; ++t) pk[t] = (short)f2bf(elu_f(acc[t] * inv));
  *(short8*)(xc + (size_t)n * 512 + L * 8) = pk;
}

// ---------------- layer-2 aggregation + fused classifier ----------------
__global__ __launch_bounds__(256) void agg2_final_kernel(const unsigned short* __restrict__ table,
    const float* __restrict__ ss, const float* __restrict__ sd,
    const int* __restrict__ row_ptr, const int* __restrict__ col,
    const float* __restrict__ mlp_w, const float* __restrict__ mlp_b,
    float* __restrict__ out, int N) {
  __shared__ float wsh[40 * 65];
  __shared__ float bsh[40];
  __shared__ float osh[4][68];
  for (int i = threadIdx.x; i < 40 * 64; i += 256) wsh[(i >> 6) * 65 + (i & 63)] = mlp_w[i];
  if (threadIdx.x < 40) bsh[threadIdx.x] = mlp_b[threadIdx.x];
  __syncthreads();

  int wid = threadIdx.x >> 6, L = threadIdx.x & 63;
  int n = blockIdx.x * 4 + wid;
  bool act = (n < N);
  float o = 0.f;
  if (act) {
    float ssn = ss[n];
    int k0 = row_ptr[n], deg = row_ptr[n + 1] - k0;
    float acc = 0.f, rs = 0.f;
    const char* base = (const char*)table;
    for (int c0 = 0; c0 < deg; c0 += 64) {
      int j = c0 + L;
      int d_l = 0;
      float e_l = 0.f;
      if (j < deg) {
        d_l = col[k0 + j];
        float s = ssn + sd[d_l];
        e_l = __expf(-fmaxf(s, ALPHA * s));
      }
      rs += e_l;
      int m = min(64, deg - c0);
      int off_l = d_l << 7;
      for (int g = 0; g < m; g += 8) {
        int gm = min(8, m - g);
        unsigned hv[8];
#pragma unroll
        for (int t = 0; t < 8; ++t) {
          if (t < gm) {
            int so = __builtin_amdgcn_readlane(off_l, g + t);
            hv[t] = *(const unsigned short*)(base + so + L * 2);
          }
        }
#pragma unroll
        for (int t = 0; t < 8; ++t) {
          if (t < gm) {
            float ew = __uint_as_float(
                (unsigned)__builtin_amdgcn_readlane(__float_as_uint(e_l), g + t));
            acc += ew * __uint_as_float(hv[t] << 16);
          }
        }
      }
    }
#pragma unroll
    for (int off = 1; off < 64; off <<= 1) rs += __shfl_xor(rs, off, 64);
    o = elu_f(acc / rs);
  }
  osh[wid][L] = o;
  __syncthreads();
  if (act && L < 40) {
    const float* wr = wsh + L * 65;
    const float* orow = osh[wid];
    float acc = bsh[L];
#pragma unroll
    for (int j = 0; j < 64; ++j) acc += orow[j] * wr[j];
    out[(size_t)n * 40 + L] = acc;
  }
}

extern "C" void kernel_launch(void* const* d_in, const int* in_sizes, int n_in,
                              void* d_out, int out_size, void* d_ws, size_t ws_size,
                              hipStream_t stream) {
  (void)n_in; (void)out_size; (void)ws_size;
  const float* x  = (const float*)d_in[0];
  const int*   ei = (const int*)d_in[1];
  const float* W  = (const float*)d_in[2];
  const float* a  = (const float*)d_in[3];
  const float* Wo = (const float*)d_in[4];
  const float* ao = (const float*)d_in[5];
  const float* mw = (const float*)d_in[6];
  const float* mb = (const float*)d_in[7];
  float* out = (float*)d_out;

  const int N = NN;
  const int E = in_sizes[1] / 2;
  const int* src = ei;
  const int* dst = ei + E;

  char* ws = (char*)d_ws;
  size_t off = 0;
  auto alloc = [&](size_t bytes) {
    char* p = ws + off;
    off = (off + bytes + 255) & ~(size_t)255;
    return p;
  };
  unsigned short* Wt  = (unsigned short*)alloc((size_t)HH * 64 * 256 * 2);
  unsigned short* Wot = (unsigned short*)alloc((size_t)64 * 512 * 2);
  unsigned short* h1b = (unsigned short*)alloc((size_t)N * 512 * 2);    // 51.2 MB
  float* ss1     = (float*)alloc((size_t)N * 8 * 4);
  float* sd1     = (float*)alloc((size_t)N * 8 * 4);
  unsigned short* xc = (unsigned short*)alloc((size_t)NPAD * 512 * 2);  // 51.25 MB
  unsigned short* h2b = (unsigned short*)alloc((size_t)N * 64 * 2);
  float* ss2     = (float*)alloc((size_t)N * 4);
  float* sd2     = (float*)alloc((size_t)N * 4);
  int*   row_ptr = (int*)  alloc((size_t)(N + 1) * 4);
  int*   nxt     = (int*)  alloc((size_t)N * 4);
  int*   nxtd    = (int*)  alloc((size_t)N * 4);
  int*   cnt2    = (int*)  alloc((size_t)2 * N * 4);
  int*   tmp2    = (int*)  alloc((size_t)2 * N * 4);
  int*   bsum2   = (int*)  alloc(128 * 4);
  int*   boffs2  = (int*)  alloc(128 * 4);
  int*   eid     = (int*)  alloc((size_t)E * 4);
  int*   colv    = (int*)  alloc((size_t)E * 4);

  int eb = (E + 255) / 256;
  int nb1024 = (N + 1023) / 1024;   // 49

  // weight prep
  hipLaunchKernelGGL(cvt_w_kernel, dim3((HH * 256 * 64 + 512 * 64 + 255) / 256), dim3(256),
                     0, stream, W, Wt, Wo, Wot);

  // CSR build, dst-quasi-sorted
  hipMemsetAsync(cnt2, 0, (size_t)2 * N * 4, stream);
  hipLaunchKernelGGL(hist_both_kernel, dim3(eb), dim3(256), 0, stream, src, dst, cnt2, N, E);
  hipLaunchKernelGGL(scan_blocks2_kernel, dim3(nb1024, 2), dim3(1024), 0, stream, cnt2, tmp2, bsum2, N);
  hipLaunchKernelGGL(scan_top2_kernel, dim3(1), dim3(128), 0, stream, bsum2, boffs2, nb1024);
  hipLaunchKernelGGL(scan_apply2_kernel, dim3(nb1024, 2), dim3(1024), 0, stream,
                     tmp2, boffs2, row_ptr, nxt, nxtd, N, E);
  hipLaunchKernelGGL(scatter_d_kernel, dim3(eb), dim3(256), 0, stream, dst, nxtd, eid, E);
  hipLaunchKernelGGL(scatter_s_kernel, dim3(eb), dim3(256), 0, stream, src, dst, eid, nxt, colv, E);

  // layer 1
  hipLaunchKernelGGL(mfma_gemm1_kernel, dim3(NPAD / 64), dim3(256), 0, stream,
                     x, Wt, a, h1b, ss1, sd1, N);
  hipLaunchKernelGGL(agg1_kernel, dim3((N + 3) / 4), dim3(256), 0, stream,
                     h1b, ss1, sd1, row_ptr, colv, xc, N);

  // layer 2
  hipLaunchKernelGGL(mfma_gemm2_kernel, dim3(NPAD / 64), dim3(256), 0, stream,
                     xc, Wot, ao, h2b, ss2, sd2, N);
  hipLaunchKernelGGL(agg2_final_kernel, dim3((N + 3) / 4), dim3(256), 0, stream,
                     h2b, ss2, sd2, row_ptr, colv, mw, mb, out, N);
}

// Round 8
// 441.408 us; speedup vs baseline: 1.1910x; 1.1910x over previous
//
#include <hip/hip_runtime.h>

#define NN 50000
#define HH 8
#define ALPHA 0.2f
#define NPAD 50048   // NN rounded up to 128

typedef short short8 __attribute__((ext_vector_type(8)));
typedef float f32x4 __attribute__((ext_vector_type(4)));

__device__ __forceinline__ float elu_f(float x) {
  return x > 0.f ? x : __expf(x) - 1.f;
}

__device__ __forceinline__ unsigned short f2bf(float f) {
  unsigned int u = __float_as_uint(f);
  unsigned int r = (u + 0x7fffu + ((u >> 16) & 1u)) >> 16;
  return (unsigned short)r;
}

// ---------------- weight prep: W [H][256][64] -> Wt [H][64][256]; Wo [512][64] -> Wot [64][512]
__global__ void cvt_w_kernel(const float* __restrict__ W, unsigned short* __restrict__ Wt,
                             const float* __restrict__ Wo, unsigned short* __restrict__ Wot) {
  int tid = blockIdx.x * 256 + threadIdx.x;
  if (tid < HH * 256 * 64) {
    int h = tid / (256 * 64);
    int rem = tid - h * 256 * 64;
    int k = rem >> 6, c = rem & 63;
    Wt[((size_t)h * 64 + c) * 256 + k] = f2bf(W[tid]);
    return;
  }
  int t2 = tid - HH * 256 * 64;
  if (t2 < 512 * 64) {
    int k = t2 >> 6, c = t2 & 63;
    Wot[(size_t)c * 512 + k] = f2bf(Wo[t2]);
  }
}

// ---------------- CSR build (simple, as in R6) ----------------
__global__ void hist_kernel(const int* __restrict__ src, int* __restrict__ cnt, int E) {
  int e = blockIdx.x * blockDim.x + threadIdx.x;
  if (e < E) atomicAdd(&cnt[src[e]], 1);
}

__global__ __launch_bounds__(1024) void scan_blocks_kernel(const int* __restrict__ cnt,
    int* __restrict__ tmp, int* __restrict__ bsum, int n) {
  __shared__ int sh[1024];
  int i = blockIdx.x * 1024 + threadIdx.x;
  int v = (i < n) ? cnt[i] : 0;
  sh[threadIdx.x] = v;
  __syncthreads();
  for (int off = 1; off < 1024; off <<= 1) {
    int t = (threadIdx.x >= off) ? sh[threadIdx.x - off] : 0;
    __syncthreads();
    sh[threadIdx.x] += t;
    __syncthreads();
  }
  if (i < n) tmp[i] = sh[threadIdx.x] - v;
  if (threadIdx.x == 1023) bsum[blockIdx.x] = sh[1023];
}

__global__ __launch_bounds__(64) void scan_top_kernel(const int* __restrict__ bsum,
    int* __restrict__ boffs, int nb) {
  int L = threadIdx.x;
  int v = (L < nb) ? bsum[L] : 0;
  int incl = v;
#pragma unroll
  for (int off = 1; off < 64; off <<= 1) {
    int t = __shfl_up(incl, off, 64);
    if (L >= off) incl += t;
  }
  if (L < nb) boffs[L] = incl - v;
}

__global__ __launch_bounds__(1024) void scan_apply_kernel(const int* __restrict__ tmp,
    const int* __restrict__ boffs, int* __restrict__ row_ptr, int* __restrict__ nxt,
    int n, int E) {
  int i = blockIdx.x * 1024 + threadIdx.x;
  if (i < n) {
    int s = tmp[i] + boffs[blockIdx.x];
    row_ptr[i] = s;
    nxt[i] = s;
  }
  if (i == 0) row_ptr[n] = E;
}

__global__ void scatter_kernel(const int* __restrict__ src, const int* __restrict__ dst,
                               int* __restrict__ nxt, int* __restrict__ col, int E) {
  int e = blockIdx.x * blockDim.x + threadIdx.x;
  if (e < E) {
    int p = atomicAdd(&nxt[src[e]], 1);
    col[p] = dst[e];
  }
}

// ---------------- layer-1 MFMA GEMM: x fp32 read directly, loop over 8 heads ----------------
__global__ __launch_bounds__(256) void mfma_gemm1_kernel(
    const float* __restrict__ X, const unsigned short* __restrict__ Bt,
    const float* __restrict__ Aatt, unsigned short* __restrict__ Cout,
    float* __restrict__ ss, float* __restrict__ sd, int N) {
  __shared__ unsigned short Bs[64][264];
  int w = threadIdx.x >> 6, L = threadIdx.x & 63;
  int quad = L >> 4, l16 = L & 15;
  int m0 = blockIdx.x * 64;
  int myrow = m0 + w * 16 + l16;
  int rowc = min(myrow, N - 1);          // clamp pad rows (results discarded)

  const float* Ar = X + (size_t)rowc * 256 + quad * 8;
  short8 areg[8];
#pragma unroll
  for (int ks = 0; ks < 8; ++ks) {
    float4 a0 = *(const float4*)(Ar + ks * 32);
    float4 a1 = *(const float4*)(Ar + ks * 32 + 4);
    areg[ks][0] = (short)f2bf(a0.x); areg[ks][1] = (short)f2bf(a0.y);
    areg[ks][2] = (short)f2bf(a0.z); areg[ks][3] = (short)f2bf(a0.w);
    areg[ks][4] = (short)f2bf(a1.x); areg[ks][5] = (short)f2bf(a1.y);
    areg[ks][6] = (short)f2bf(a1.z); areg[ks][7] = (short)f2bf(a1.w);
  }

  for (int y = 0; y < HH; ++y) {
    __syncthreads();
    {
      const unsigned short* Bsrc = Bt + (size_t)y * 64 * 256;
      for (int c = threadIdx.x; c < 2048; c += 256) {
        int n = c >> 5;
        int kq = (c & 31) << 3;
        *(uint4*)&Bs[n][kq] = *(const uint4*)(Bsrc + (size_t)n * 256 + kq);
      }
    }
    __syncthreads();

    f32x4 acc[4];
#pragma unroll
    for (int nt = 0; nt < 4; ++nt) acc[nt] = (f32x4)(0.f);
#pragma unroll
    for (int ks = 0; ks < 8; ++ks) {
#pragma unroll
      for (int nt = 0; nt < 4; ++nt) {
        short8 b = *(const short8*)&Bs[l16 + 16 * nt][ks * 32 + quad * 8];
        acc[nt] = __builtin_amdgcn_mfma_f32_16x16x32_bf16(areg[ks], b, acc[nt], 0, 0, 0);
      }
    }

    float as[4], ad[4];
#pragma unroll
    for (int nt = 0; nt < 4; ++nt) {
      as[nt] = Aatt[y * 128 + l16 + 16 * nt];
      ad[nt] = Aatt[y * 128 + 64 + l16 + 16 * nt];
    }
#pragma unroll
    for (int reg = 0; reg < 4; ++reg) {
      float p = 0.f, q = 0.f;
#pragma unroll
      for (int nt = 0; nt < 4; ++nt) {
        p += acc[nt][reg] * as[nt];
        q += acc[nt][reg] * ad[nt];
      }
#pragma unroll
      for (int off = 1; off < 16; off <<= 1) {
        p += __shfl_xor(p, off, 64);
        q += __shfl_xor(q, off, 64);
      }
      int row = m0 + w * 16 + quad * 4 + reg;
      if (l16 == 0 && row < N) {
        ss[(size_t)row * 8 + y] = p;
        sd[(size_t)row * 8 + y] = q;
      }
    }
#pragma unroll
    for (int reg = 0; reg < 4; ++reg) {
      int row = m0 + w * 16 + quad * 4 + reg;
      if (row < N) {
#pragma unroll
        for (int nt = 0; nt < 4; ++nt)
          Cout[(size_t)row * 512 + y * 64 + l16 + 16 * nt] = f2bf(acc[nt][reg]);
      }
    }
  }
}

// ---------------- layer-2 MFMA GEMM ----------------
__global__ __launch_bounds__(256) void mfma_gemm2_kernel(
    const unsigned short* __restrict__ A, const unsigned short* __restrict__ Bt,
    const float* __restrict__ Aatt, unsigned short* __restrict__ Cout,
    float* __restrict__ ss, float* __restrict__ sd, int N) {
  __shared__ unsigned short Bs[64][520];
  {
    for (int c = threadIdx.x; c < 4096; c += 256) {
      int n = c >> 6;
      int kq = (c & 63) << 3;
      *(uint4*)&Bs[n][kq] = *(const uint4*)(Bt + (size_t)n * 512 + kq);
    }
  }
  __syncthreads();

  int w = threadIdx.x >> 6, L = threadIdx.x & 63;
  int quad = L >> 4, l16 = L & 15;
  int m0 = blockIdx.x * 64;
  int myrow = m0 + w * 16 + l16;
  const unsigned short* Ar = A + (size_t)myrow * 512 + quad * 8;

  f32x4 acc[4];
#pragma unroll
  for (int nt = 0; nt < 4; ++nt) acc[nt] = (f32x4)(0.f);

  short8 a_cur = *(const short8*)(Ar);
  for (int k0 = 0; k0 < 512; k0 += 32) {
    short8 a_nxt;
    if (k0 + 32 < 512) a_nxt = *(const short8*)(Ar + k0 + 32);
#pragma unroll
    for (int nt = 0; nt < 4; ++nt) {
      short8 b = *(const short8*)&Bs[l16 + 16 * nt][k0 + quad * 8];
      acc[nt] = __builtin_amdgcn_mfma_f32_16x16x32_bf16(a_cur, b, acc[nt], 0, 0, 0);
    }
    a_cur = a_nxt;
  }

  float as[4], ad[4];
#pragma unroll
  for (int nt = 0; nt < 4; ++nt) {
    as[nt] = Aatt[l16 + 16 * nt];
    ad[nt] = Aatt[64 + l16 + 16 * nt];
  }
#pragma unroll
  for (int reg = 0; reg < 4; ++reg) {
    float p = 0.f, q = 0.f;
#pragma unroll
    for (int nt = 0; nt < 4; ++nt) {
      p += acc[nt][reg] * as[nt];
      q += acc[nt][reg] * ad[nt];
    }
#pragma unroll
    for (int off = 1; off < 16; off <<= 1) {
      p += __shfl_xor(p, off, 64);
      q += __shfl_xor(q, off, 64);
    }
    int row = m0 + w * 16 + quad * 4 + reg;
    if (l16 == 0 && row < N) { ss[row] = p; sd[row] = q; }
  }
#pragma unroll
  for (int reg = 0; reg < 4; ++reg) {
    int row = m0 + w * 16 + quad * 4 + reg;
    if (row < N) {
#pragma unroll
      for (int nt = 0; nt < 4; ++nt)
        Cout[(size_t)row * 64 + l16 + 16 * nt] = f2bf(acc[nt][reg]);
    }
  }
}

// ---------------- layer-1 aggregation: (node, feature-half) per wave, XCD-partitioned ----------------
// table bf16 [N][512] (head-major cols); wave handles half p (heads 4p..4p+3, 512B of each row).
// half p is tied to blockIdx%8 so (with round-robin XCD dispatch) XCDs 0-3 only touch half 0.
// Lane L: head hq=L>>4 (within half), 4 feats (L&15)*4; e-phase covers 16 edges x 4 heads.
__global__ __launch_bounds__(256) void agg1_kernel(const unsigned short* __restrict__ table,
    const float* __restrict__ ss, const float* __restrict__ sd,
    const int* __restrict__ row_ptr, const int* __restrict__ col,
    unsigned short* __restrict__ xc, int N) {
  int bid = blockIdx.x;
  int r8 = bid & 7;
  int p = r8 >> 2;                       // feature half (0: heads 0-3, 1: heads 4-7)
  int nb = ((bid >> 3) << 2) | (r8 & 3); // node-block index, each (nb,p) exactly once
  int wid = threadIdx.x >> 6, L = threadIdx.x & 63;
  int n = nb * 4 + wid;
  if (n >= N) return;
  int hq = L >> 4;
  int h = p * 4 + hq;
  int el = L & 15;
  float ssn = ss[n * 8 + h];
  int k0 = row_ptr[n], deg = row_ptr[n + 1] - k0;
  float acc[4] = {0.f, 0.f, 0.f, 0.f};
  float rs = 0.f;
  const char* tb = (const char*)table + p * 512;  // byte offset of this half within each 1KB row

  for (int c0 = 0; c0 < deg; c0 += 64) {
    int j = c0 + L;
    int d_l = (j < deg) ? col[k0 + j] : 0;
    int m = min(64, deg - c0);
    for (int g = 0; g < m; g += 16) {
      // e-phase: lane (hq*16+el) -> e for (edge g+el, head p*4+hq)
      int eoff = g + el;
      int de = __shfl(d_l, eoff, 64);
      float s = ssn + sd[(size_t)de * 8 + h];
      float e = __expf(-fmaxf(s, ALPHA * s));
      if (eoff >= m) e = 0.f;
      rs += e;
      int gm = min(16, m - g);
      // 16 independent half-row gathers (dwordx2, scalar-addressed via readlane)
      uint2 rv[16];
#pragma unroll
      for (int t = 0; t < 16; ++t) {
        if (t < gm) {
          int dg = __builtin_amdgcn_readlane(d_l, g + t);
          rv[t] = *(const uint2*)(tb + (size_t)dg * 1024 + L * 8);
        }
      }
#pragma unroll
      for (int t = 0; t < 16; ++t) {
        if (t < gm) {
          float ew = __shfl(e, (hq << 4) + t, 64);
          acc[0] += ew * __uint_as_float(rv[t].x << 16);
          acc[1] += ew * __uint_as_float(rv[t].x & 0xffff0000u);
          acc[2] += ew * __uint_as_float(rv[t].y << 16);
          acc[3] += ew * __uint_as_float(rv[t].y & 0xffff0000u);
        }
      }
    }
  }
  // rs: sum across the 16 lanes of this head group
  rs += __shfl_xor(rs, 1, 64);
  rs += __shfl_xor(rs, 2, 64);
  rs += __shfl_xor(rs, 4, 64);
  rs += __shfl_xor(rs, 8, 64);
  float inv = 1.f / rs;
  ushort4 pk;
  pk.x = f2bf(elu_f(acc[0] * inv));
  pk.y = f2bf(elu_f(acc[1] * inv));
  pk.z = f2bf(elu_f(acc[2] * inv));
  pk.w = f2bf(elu_f(acc[3] * inv));
  *(ushort4*)(xc + (size_t)n * 512 + p * 256 + L * 4) = pk;
}

// ---------------- layer-2 aggregation + fused classifier ----------------
__global__ __launch_bounds__(256) void agg2_final_kernel(const unsigned short* __restrict__ table,
    const float* __restrict__ ss, const float* __restrict__ sd,
    const int* __restrict__ row_ptr, const int* __restrict__ col,
    const float* __restrict__ mlp_w, const float* __restrict__ mlp_b,
    float* __restrict__ out, int N) {
  __shared__ float wsh[40 * 65];
  __shared__ float bsh[40];
  __shared__ float osh[4][68];
  for (int i = threadIdx.x; i < 40 * 64; i += 256) wsh[(i >> 6) * 65 + (i & 63)] = mlp_w[i];
  if (threadIdx.x < 40) bsh[threadIdx.x] = mlp_b[threadIdx.x];
  __syncthreads();

  int wid = threadIdx.x >> 6, L = threadIdx.x & 63;
  int n = blockIdx.x * 4 + wid;
  bool act = (n < N);
  float o = 0.f;
  if (act) {
    float ssn = ss[n];
    int k0 = row_ptr[n], deg = row_ptr[n + 1] - k0;
    float acc = 0.f, rs = 0.f;
    const char* base = (const char*)table;
    for (int c0 = 0; c0 < deg; c0 += 64) {
      int j = c0 + L;
      int d_l = 0;
      float e_l = 0.f;
      if (j < deg) {
        d_l = col[k0 + j];
        float s = ssn + sd[d_l];
        e_l = __expf(-fmaxf(s, ALPHA * s));
      }
      rs += e_l;
      int m = min(64, deg - c0);
      int off_l = d_l << 7;
      for (int g = 0; g < m; g += 8) {
        int gm = min(8, m - g);
        unsigned hv[8];
#pragma unroll
        for (int t = 0; t < 8; ++t) {
          if (t < gm) {
            int so = __builtin_amdgcn_readlane(off_l, g + t);
            hv[t] = *(const unsigned short*)(base + so + L * 2);
          }
        }
#pragma unroll
        for (int t = 0; t < 8; ++t) {
          if (t < gm) {
            float ew = __uint_as_float(
                (unsigned)__builtin_amdgcn_readlane(__float_as_uint(e_l), g + t));
            acc += ew * __uint_as_float(hv[t] << 16);
          }
        }
      }
    }
#pragma unroll
    for (int off = 1; off < 64; off <<= 1) rs += __shfl_xor(rs, off, 64);
    o = elu_f(acc / rs);
  }
  osh[wid][L] = o;
  __syncthreads();
  if (act && L < 40) {
    const float* wr = wsh + L * 65;
    const float* orow = osh[wid];
    float acc = bsh[L];
#pragma unroll
    for (int j = 0; j < 64; ++j) acc += orow[j] * wr[j];
    out[(size_t)n * 40 + L] = acc;
  }
}

extern "C" void kernel_launch(void* const* d_in, const int* in_sizes, int n_in,
                              void* d_out, int out_size, void* d_ws, size_t ws_size,
                              hipStream_t stream) {
  (void)n_in; (void)out_size; (void)ws_size;
  const float* x  = (const float*)d_in[0];
  const int*   ei = (const int*)d_in[1];
  const float* W  = (const float*)d_in[2];
  const float* a  = (const float*)d_in[3];
  const float* Wo = (const float*)d_in[4];
  const float* ao = (const float*)d_in[5];
  const float* mw = (const float*)d_in[6];
  const float* mb = (const float*)d_in[7];
  float* out = (float*)d_out;

  const int N = NN;
  const int E = in_sizes[1] / 2;
  const int* src = ei;
  const int* dst = ei + E;

  char* ws = (char*)d_ws;
  size_t off = 0;
  auto alloc = [&](size_t bytes) {
    char* p = ws + off;
    off = (off + bytes + 255) & ~(size_t)255;
    return p;
  };
  unsigned short* Wt  = (unsigned short*)alloc((size_t)HH * 64 * 256 * 2);
  unsigned short* Wot = (unsigned short*)alloc((size_t)64 * 512 * 2);
  unsigned short* h1b = (unsigned short*)alloc((size_t)N * 512 * 2);    // 51.2 MB
  float* ss1     = (float*)alloc((size_t)N * 8 * 4);
  float* sd1     = (float*)alloc((size_t)N * 8 * 4);
  unsigned short* xc = (unsigned short*)alloc((size_t)NPAD * 512 * 2);  // 51.25 MB
  unsigned short* h2b = (unsigned short*)alloc((size_t)N * 64 * 2);
  float* ss2     = (float*)alloc((size_t)N * 4);
  float* sd2     = (float*)alloc((size_t)N * 4);
  int*   row_ptr = (int*)  alloc((size_t)(N + 1) * 4);
  int*   nxt     = (int*)  alloc((size_t)N * 4);
  int*   cnt     = (int*)  alloc((size_t)N * 4);
  int*   tmp     = (int*)  alloc((size_t)N * 4);
  int*   bsum    = (int*)  alloc(64 * 4);
  int*   boffs   = (int*)  alloc(64 * 4);
  int*   colv    = (int*)  alloc((size_t)E * 4);

  int eb = (E + 255) / 256;
  int nb1024 = (N + 1023) / 1024;   // 49

  // weight prep
  hipLaunchKernelGGL(cvt_w_kernel, dim3((HH * 256 * 64 + 512 * 64 + 255) / 256), dim3(256),
                     0, stream, W, Wt, Wo, Wot);

  // CSR (simple single-scatter build)
  hipMemsetAsync(cnt, 0, (size_t)N * 4, stream);
  hipLaunchKernelGGL(hist_kernel, dim3(eb), dim3(256), 0, stream, src, cnt, E);
  hipLaunchKernelGGL(scan_blocks_kernel, dim3(nb1024), dim3(1024), 0, stream, cnt, tmp, bsum, N);
  hipLaunchKernelGGL(scan_top_kernel, dim3(1), dim3(64), 0, stream, bsum, boffs, nb1024);
  hipLaunchKernelGGL(scan_apply_kernel, dim3(nb1024), dim3(1024), 0, stream, tmp, boffs, row_ptr, nxt, N, E);
  hipLaunchKernelGGL(scatter_kernel, dim3(eb), dim3(256), 0, stream, src, dst, nxt, colv, E);

  // layer 1
  hipLaunchKernelGGL(mfma_gemm1_kernel, dim3(NPAD / 64), dim3(256), 0, stream,
                     x, Wt, a, h1b, ss1, sd1, N);
  // grid = 2 halves x 12500 node-blocks; (nb, p) derived from blockIdx inside
  hipLaunchKernelGGL(agg1_kernel, dim3(2 * ((N + 3) / 4)), dim3(256), 0, stream,
                     h1b, ss1, sd1, row_ptr, colv, xc, N);

  // layer 2
  hipLaunchKernelGGL(mfma_gemm2_kernel, dim3(NPAD / 64), dim3(256), 0, stream,
                     xc, Wot, ao, h2b, ss2, sd2, N);
  hipLaunchKernelGGL(agg2_final_kernel, dim3((N + 3) / 4), dim3(256), 0, stream,
                     h2b, ss2, sd2, row_ptr, colv, mw, mb, out, N);
}